// Round 6
// baseline (413.125 us; speedup 1.0000x reference)
//
#include <hip/hip_runtime.h>

typedef unsigned int u32;
typedef unsigned short u16;
typedef __attribute__((ext_vector_type(8))) short short8;   // 8 x bf16 (guide-verified frag type)
typedef __attribute__((ext_vector_type(4))) float f32x4;

#define POOLCAP 65536
#define IDXMASK 0x1ffff   // src index lives in bits 0..16; deg in bits 17..31

__device__ __forceinline__ u16 f2bf(float f) {
    u32 u = __float_as_uint(f);
    u32 r = (u + 0x7fffu + ((u >> 16) & 1u)) >> 16;   // RNE
    return (u16)r;
}
__device__ __forceinline__ float bf2f(u32 lo16) { return __uint_as_float(lo16 << 16); }

// packed accumulate: a[i] += {lo(w), hi(w)}
__device__ __forceinline__ void acc_u4p(float2* a, uint4 v) {
    u32 w[4] = {v.x, v.y, v.z, v.w};
#pragma unroll
    for (int i = 0; i < 4; i++) {
        a[i].x += __uint_as_float(w[i] << 16);
        a[i].y += __uint_as_float(w[i] & 0xffff0000u);
    }
}

// ---------------- prep ----------------

__global__ __launch_bounds__(256) void prep_w_all(const float* __restrict__ ws0, const float* __restrict__ wn0, u16* __restrict__ wt0,
                                                  const float* __restrict__ ws1, const float* __restrict__ wn1, u16* __restrict__ wt1,
                                                  const float* __restrict__ ws2, const float* __restrict__ wn2, u16* __restrict__ wt2) {
    int bid = blockIdx.x;
    const float *ws, *wn;
    u16* wt;
    int dout, HW, local;
    if (bid < 128)      { ws = ws0; wn = wn0; wt = wt0; dout = 128; HW = 128; local = bid; }
    else if (bid < 256) { ws = ws1; wn = wn1; wt = wt1; dout = 128; HW = 128; local = bid - 128; }
    else                { ws = ws2; wn = wn2; wt = wt2; dout = 47;  HW = 64;  local = bid - 256; }
    int idx = local * 256 + threadIdx.x;   // idx = n*128 + k
    int n = idx >> 7, k = idx & 127;
    float v = 0.f;
    if (n < HW) { if (n < dout) v = ws[k * dout + n]; }
    else { int nn = n - HW; if (nn < dout) v = wn[k * dout + nn]; }
    wt[idx] = f2bf(v);
}

// ---------------- CSR build (fixed-stride 32-slot edge table, deg packed in high bits) ----------------

__global__ __launch_bounds__(256) void hist256(const int* __restrict__ dst,
                                               int* __restrict__ bcnt, int E) {
    __shared__ int bins[256];
    bins[threadIdx.x] = 0;
    __syncthreads();
    int gid = blockIdx.x * 256 + threadIdx.x;
    int stride = gridDim.x * 256;
    const int4* d4 = (const int4*)dst;
    int n4 = E >> 2;
    for (int k = gid; k < n4; k += stride) {
        int4 v = d4[k];
        atomicAdd(&bins[v.x >> 9], 1);
        atomicAdd(&bins[v.y >> 9], 1);
        atomicAdd(&bins[v.z >> 9], 1);
        atomicAdd(&bins[v.w >> 9], 1);
    }
    for (int k = (n4 << 2) + gid; k < E; k += stride)
        atomicAdd(&bins[dst[k] >> 9], 1);
    __syncthreads();
    int b = bins[threadIdx.x];
    if (b) atomicAdd(&bcnt[threadIdx.x], b);
}

__global__ __launch_bounds__(256) void scan256(const int* __restrict__ bcnt,
                                               int* __restrict__ boff,
                                               int* __restrict__ cursor) {
    __shared__ int sm[256];
    int t = threadIdx.x;
    int v = bcnt[t];
    sm[t] = v;
    __syncthreads();
    for (int off = 1; off < 256; off <<= 1) {
        int u = (t >= off) ? sm[t - off] : 0;
        __syncthreads();
        sm[t] += u;
        __syncthreads();
    }
    int excl = sm[t] - v;
    boff[t] = excl;
    cursor[t] = excl;
    if (t == 255) boff[256] = sm[255];   // == E
}

// multisplit pass 1: tile -> LDS bucket-compaction -> contiguous bucket segments
#define TILE 4096
__global__ __launch_bounds__(512) void bucket_scatter(const int* __restrict__ src,
                                                      const int* __restrict__ dst,
                                                      int* __restrict__ cursor,
                                                      uint2* __restrict__ pairs, int E) {
    __shared__ uint2 sp[TILE];                         // 32 KB
    __shared__ int s_cnt[256], s_off[256], s_gpos[256], s_cnt2[256];
    const int tid = threadIdx.x;
    const int base = blockIdx.x * TILE;
    const int tn = min(TILE, E - base);
    if (tid < 256) { s_cnt[tid] = 0; s_cnt2[tid] = 0; }
    __syncthreads();
    int d[8], s[8];
#pragma unroll
    for (int j = 0; j < 8; j++) {
        int k = tid + j * 512;
        if (k < tn) {
            d[j] = dst[base + k];
            s[j] = src[base + k];
            atomicAdd(&s_cnt[d[j] >> 9], 1);
        } else d[j] = -1;
    }
    __syncthreads();
    if (tid < 256) s_off[tid] = s_cnt[tid];
    __syncthreads();
    for (int off = 1; off < 256; off <<= 1) {
        int v = 0;
        if (tid < 256 && tid >= off) v = s_off[tid - off];
        __syncthreads();
        if (tid < 256) s_off[tid] += v;
        __syncthreads();
    }
    if (tid < 256 && s_cnt[tid] > 0) s_gpos[tid] = atomicAdd(&cursor[tid], s_cnt[tid]);
    __syncthreads();
#pragma unroll
    for (int j = 0; j < 8; j++) {
        if (d[j] >= 0) {
            int b = d[j] >> 9;
            int p = atomicAdd(&s_cnt2[b], 1);
            sp[s_off[b] - s_cnt[b] + p] = make_uint2((u32)d[j], (u32)s[j]);
        }
    }
    __syncthreads();
    for (int k = tid; k < tn; k += 512) {
        uint2 pr = sp[k];
        int b = (int)(pr.x >> 9);
        pairs[s_gpos[b] + (k - (s_off[b] - s_cnt[b]))] = pr;
    }
}

// multisplit pass 2: FIXED-STRIDE placement.
//   colsF[node*32 + p] = (deg<<17) | src  for the first 32 edges (sentinel src = Nn -> zero row).
//   deg is wave-uniform at agg time -> enables SCALAR gating of accumulate rounds.
//   Edges past 32 -> tiny overflow pool. invd computed here.
#define LDSCAP 12288
__global__ __launch_bounds__(512) void build_csr3(const uint2* __restrict__ pairs,
                                                  const int* __restrict__ boff,
                                                  float* __restrict__ invd,
                                                  int* __restrict__ colsF,
                                                  uint2* __restrict__ pool,
                                                  int* __restrict__ gcnt,
                                                  int Nn) {
    __shared__ int s_pack[LDSCAP];                     // 48 KB stash: (dl<<17)|src
    __shared__ int s_fix[512 * 32];                    // 64 KB fixed table
    __shared__ int s_cnt[512];
    const int tid = threadIdx.x;
    const int d0 = blockIdx.x * 512;
    const int nd = min(512, Nn - d0);
    const int base = boff[blockIdx.x];
    const int n = boff[blockIdx.x + 1] - base;
    const bool fit = (n <= LDSCAP);
    s_cnt[tid] = 0;
    {   // sentinel fill
        int4 sv4 = make_int4(Nn, Nn, Nn, Nn);
        int4* p4 = (int4*)s_fix;
        for (int k = tid; k < 512 * 32 / 4; k += 512) p4[k] = sv4;
    }
    __syncthreads();
    if (fit) {
        for (int k = tid; k < n; k += 512) {
            uint2 pr = pairs[base + k];
            int dl = (int)pr.x - d0;
            atomicAdd(&s_cnt[dl], 1);
            s_pack[k] = (dl << 17) | (int)pr.y;        // src < 2^17
        }
    } else {                                           // fallback (never expected)
        for (int k = tid; k < n; k += 512) {
            uint2 pr = pairs[base + k];
            atomicAdd(&s_cnt[(int)pr.x - d0], 1);
        }
    }
    __syncthreads();
    if (tid < nd) invd[d0 + tid] = 1.0f / (float)max(s_cnt[tid], 1);
    s_cnt[tid] = 0;                                    // own-slot reset
    __syncthreads();
    if (fit) {
        for (int k = tid; k < n; k += 512) {
            int pk = s_pack[k];
            int dl = pk >> 17, sc = pk & IDXMASK;
            int p = atomicAdd(&s_cnt[dl], 1);
            if (p < 32) s_fix[dl * 32 + p] = sc;
            else {
                int q = atomicAdd(gcnt, 1);
                if (q < POOLCAP) pool[q] = make_uint2((u32)(d0 + dl), (u32)sc);
            }
        }
    } else {
        for (int k = tid; k < n; k += 512) {
            uint2 pr = pairs[base + k];
            int dl = (int)pr.x - d0;
            int p = atomicAdd(&s_cnt[dl], 1);
            if (p < 32) s_fix[dl * 32 + p] = (int)pr.y;
            else {
                int q = atomicAdd(gcnt, 1);
                if (q < POOLCAP) pool[q] = make_uint2((u32)(d0 + dl), pr.y);
            }
        }
    }
    __syncthreads();
    // writeback: OR deg (capped to 15 bits) into every slot's high bits
    int4* dst4 = (int4*)(colsF + (size_t)d0 * 32);
    const int4* s4p = (const int4*)s_fix;
    for (int k = tid; k < 512 * 32 / 4; k += 512) {
        int4 v = s4p[k];
        int dg = min(s_cnt[k >> 3], 0x7fff) << 17;     // k>>3: 8 int4 per node
        v.x |= dg; v.y |= dg; v.z |= dg; v.w |= dg;
        dst4[k] = v;
    }
}

// ---------------- fused GEMM: C[M][NCOLS] = A[M][128] @ Bt^T  (fp32 acc) ----------------
#define KDIM 128
#define KP 136

template <int NCOLS, bool AF32>
__global__ __launch_bounds__(256) void gemm_bf16(const void* __restrict__ Ap,
                                                 const u16* __restrict__ Bt,
                                                 u16* __restrict__ C, int M) {
    __shared__ u16 As[64 * KP];
    __shared__ u16 Bs[128 * KP];
    const int row0 = blockIdx.x * 64;
    const int col0 = blockIdx.y * 128;
    const int tid = threadIdx.x;

#pragma unroll
    for (int i = 0; i < 4; i++) {
        int idx = tid + i * 256;
        int r = idx >> 4, c = idx & 15;
        uint4 v = make_uint4(0, 0, 0, 0);
        if (row0 + r < M) {
            if (AF32) {
                const float* Af = (const float*)Ap;
                const float4* rowp = (const float4*)(Af + (size_t)(row0 + r) * KDIM);
                float4 f0 = rowp[2 * c];
                float4 f1 = rowp[2 * c + 1];
                v.x = (u32)f2bf(f0.x) | ((u32)f2bf(f0.y) << 16);
                v.y = (u32)f2bf(f0.z) | ((u32)f2bf(f0.w) << 16);
                v.z = (u32)f2bf(f1.x) | ((u32)f2bf(f1.y) << 16);
                v.w = (u32)f2bf(f1.z) | ((u32)f2bf(f1.w) << 16);
            } else {
                const u16* Ab = (const u16*)Ap;
                v = ((const uint4*)(Ab + (size_t)(row0 + r) * KDIM))[c];
            }
        }
        ((uint4*)(As + r * KP))[c] = v;
    }
#pragma unroll
    for (int i = 0; i < 8; i++) {
        int idx = tid + i * 256;
        int r = idx >> 4, c = idx & 15;
        uint4 v = ((const uint4*)(Bt + (size_t)(col0 + r) * KDIM))[c];
        ((uint4*)(Bs + r * KP))[c] = v;
    }
    __syncthreads();

    const int lane = tid & 63, wave = tid >> 6;
    const int quad = lane >> 4, l16 = lane & 15;
    const int wcol = wave * 32;

    f32x4 acc[4][2];
#pragma unroll
    for (int mt = 0; mt < 4; mt++)
#pragma unroll
        for (int nt = 0; nt < 2; nt++) acc[mt][nt] = (f32x4){0.f, 0.f, 0.f, 0.f};

#pragma unroll
    for (int kc = 0; kc < 4; kc++) {
        short8 a[4], b[2];
#pragma unroll
        for (int mt = 0; mt < 4; mt++)
            a[mt] = *(const short8*)(As + (size_t)(mt * 16 + l16) * KP + kc * 32 + quad * 8);
#pragma unroll
        for (int nt = 0; nt < 2; nt++)
            b[nt] = *(const short8*)(Bs + (size_t)(wcol + nt * 16 + l16) * KP + kc * 32 + quad * 8);
#pragma unroll
        for (int mt = 0; mt < 4; mt++)
#pragma unroll
            for (int nt = 0; nt < 2; nt++)
                acc[mt][nt] = __builtin_amdgcn_mfma_f32_16x16x32_bf16(a[mt], b[nt], acc[mt][nt], 0, 0, 0);
    }

    __syncthreads();
#pragma unroll
    for (int mt = 0; mt < 4; mt++)
#pragma unroll
        for (int i = 0; i < 4; i++) {
            int rl = mt * 16 + quad * 4 + i;
#pragma unroll
            for (int nt = 0; nt < 2; nt++)
                As[rl * KP + wcol + nt * 16 + l16] = f2bf(acc[mt][nt][i]);
        }
    __syncthreads();
#pragma unroll
    for (int it = 0; it < 4; it++) {
        int idx = tid + it * 256;
        int r = idx >> 4, c8 = idx & 15;
        if (row0 + r < M)
            *(uint4*)(C + (size_t)(row0 + r) * NCOLS + col0 + c8 * 8) =
                *(const uint4*)(As + r * KP + c8 * 8);
    }
}

// ---------------- 128-col aggregation, fixed-stride + SCALAR deg-gated accumulate ----------------
// colsF[node*32+p] = (deg<<17)|src. All 8 gathers issue unconditionally (sentinel = hot
// zero-row line, full MLP); accumulate round k is skipped via s_cbranch when deg <= 4k
// (deg is wave-uniform -> readfirstlane -> SGPR, zero divergence). Skipped accs were +0.0.
template <bool RELU>
__global__ __launch_bounds__(256) void agg128f_k(const u16* __restrict__ out2,
                                                 const int* __restrict__ colsF,
                                                 const float* __restrict__ invd,
                                                 const float* __restrict__ bias,
                                                 u16* __restrict__ outp, int Mn) {
    int wave = threadIdx.x >> 6, lane = threadIdx.x & 63;
    int node = blockIdx.x * 4 + wave;
    if (node >= Mn) return;
    int sub = lane >> 4, l16 = lane & 15;
    const u16* tb = out2 + 128 + 8 * l16;
    const int* cp = colsF + node * 32 + sub;
    int s0 = cp[0],  s1 = cp[4],  s2 = cp[8],  s3 = cp[12];
    int s4 = cp[16], s5 = cp[20], s6 = cp[24], s7 = cp[28];
    const int deg = __builtin_amdgcn_readfirstlane(s0 >> 17);   // wave-uniform degree -> SGPR
    s0 &= IDXMASK; s1 &= IDXMASK; s2 &= IDXMASK; s3 &= IDXMASK;
    s4 &= IDXMASK; s5 &= IDXMASK; s6 &= IDXMASK; s7 &= IDXMASK;
    float id = invd[node];
    uint4 sv = *(const uint4*)(out2 + (size_t)node * 256 + 8 * l16);
    float4 b0 = *(const float4*)(bias + 8 * l16);
    float4 b1 = *(const float4*)(bias + 8 * l16 + 4);
    uint4 v0 = *(const uint4*)(tb + (size_t)s0 * 256);
    uint4 v1 = *(const uint4*)(tb + (size_t)s1 * 256);
    uint4 v2 = *(const uint4*)(tb + (size_t)s2 * 256);
    uint4 v3 = *(const uint4*)(tb + (size_t)s3 * 256);
    uint4 v4 = *(const uint4*)(tb + (size_t)s4 * 256);
    uint4 v5 = *(const uint4*)(tb + (size_t)s5 * 256);
    uint4 v6 = *(const uint4*)(tb + (size_t)s6 * 256);
    uint4 v7 = *(const uint4*)(tb + (size_t)s7 * 256);
    float2 a[4];
#pragma unroll
    for (int i = 0; i < 4; i++) a[i] = make_float2(0.f, 0.f);
    acc_u4p(a, v0);
    if (deg > 4)  acc_u4p(a, v1);
    if (deg > 8)  acc_u4p(a, v2);
    if (deg > 12) acc_u4p(a, v3);
    if (deg > 16) {
        acc_u4p(a, v4);
        if (deg > 20) acc_u4p(a, v5);
        if (deg > 24) acc_u4p(a, v6);
        if (deg > 28) acc_u4p(a, v7);
    }
    float af[8] = {a[0].x, a[0].y, a[1].x, a[1].y, a[2].x, a[2].y, a[3].x, a[3].y};
#pragma unroll
    for (int j = 0; j < 8; j++) {
        af[j] += __shfl_xor(af[j], 16); af[j] += __shfl_xor(af[j], 32);
    }
    if (sub == 0) {
        float o0 = bf2f(sv.x & 0xffffu) + af[0] * id + b0.x;
        float o1 = bf2f(sv.x >> 16)     + af[1] * id + b0.y;
        float o2 = bf2f(sv.y & 0xffffu) + af[2] * id + b0.z;
        float o3 = bf2f(sv.y >> 16)     + af[3] * id + b0.w;
        float o4 = bf2f(sv.z & 0xffffu) + af[4] * id + b1.x;
        float o5 = bf2f(sv.z >> 16)     + af[5] * id + b1.y;
        float o6 = bf2f(sv.w & 0xffffu) + af[6] * id + b1.z;
        float o7 = bf2f(sv.w >> 16)     + af[7] * id + b1.w;
        if (RELU) {
            o0 = fmaxf(o0, 0.f); o1 = fmaxf(o1, 0.f); o2 = fmaxf(o2, 0.f); o3 = fmaxf(o3, 0.f);
            o4 = fmaxf(o4, 0.f); o5 = fmaxf(o5, 0.f); o6 = fmaxf(o6, 0.f); o7 = fmaxf(o7, 0.f);
        }
        uint4 w;
        w.x = (u32)f2bf(o0) | ((u32)f2bf(o1) << 16);
        w.y = (u32)f2bf(o2) | ((u32)f2bf(o3) << 16);
        w.z = (u32)f2bf(o4) | ((u32)f2bf(o5) << 16);
        w.w = (u32)f2bf(o6) | ((u32)f2bf(o7) << 16);
        *(uint4*)(outp + (size_t)node * 128 + 8 * l16) = w;
    }
}

// ---------------- layer-2 aggregation, fixed-stride + scalar deg-gated accumulate ----------------
__global__ __launch_bounds__(256) void agg_out8f_k(const u16* __restrict__ out2,
                                                   const int* __restrict__ colsF,
                                                   const float* __restrict__ invd,
                                                   const float* __restrict__ bias,
                                                   float* __restrict__ outp, int Mn) {
    int wave = threadIdx.x >> 6, lane = threadIdx.x & 63;
    int node = blockIdx.x * 4 + wave;
    if (node >= Mn) return;
    int e8 = lane >> 3, l8 = lane & 7;
    const u16* tb = out2 + 64 + 8 * l8;
    const int* cp = colsF + node * 32 + e8;
    int s0 = cp[0], s1 = cp[8], s2 = cp[16], s3 = cp[24];
    const int deg = __builtin_amdgcn_readfirstlane(s0 >> 17);
    s0 &= IDXMASK; s1 &= IDXMASK; s2 &= IDXMASK; s3 &= IDXMASK;
    float id = invd[node];
    uint4 sv = *(const uint4*)(out2 + (size_t)node * 128 + 8 * l8);
    uint4 v0 = *(const uint4*)(tb + (size_t)s0 * 128);
    uint4 v1 = *(const uint4*)(tb + (size_t)s1 * 128);
    uint4 v2 = *(const uint4*)(tb + (size_t)s2 * 128);
    uint4 v3 = *(const uint4*)(tb + (size_t)s3 * 128);
    float2 a[4];
#pragma unroll
    for (int i = 0; i < 4; i++) a[i] = make_float2(0.f, 0.f);
    acc_u4p(a, v0);
    if (deg > 8)  acc_u4p(a, v1);
    if (deg > 16) acc_u4p(a, v2);
    if (deg > 24) acc_u4p(a, v3);
    float af[8] = {a[0].x, a[0].y, a[1].x, a[1].y, a[2].x, a[2].y, a[3].x, a[3].y};
#pragma unroll
    for (int j = 0; j < 8; j++) {
        af[j] += __shfl_xor(af[j], 8); af[j] += __shfl_xor(af[j], 16); af[j] += __shfl_xor(af[j], 32);
    }
    if (e8 == 0) {
        u32 sw[4] = {sv.x, sv.y, sv.z, sv.w};
        float* orow = outp + (size_t)node * 47;
#pragma unroll
        for (int j = 0; j < 8; j++) {
            int c = 8 * l8 + j;
            if (c < 47) {
                float s = bf2f((j & 1) ? (sw[j >> 1] >> 16) : (sw[j >> 1] & 0xffffu));
                orow[c] = s + af[j] * id + bias[c];
            }
        }
    }
}

// ---------------- overflow recompute (deg>32 nodes; ~tens of pool entries) ----------------
template <int MODE>   // 0: 128-col relu bf16 out ; 1: 47-col fp32 out
__global__ __launch_bounds__(256) void oflow_k(const uint2* __restrict__ pool,
                                               const int* __restrict__ gcnt,
                                               const int* __restrict__ colsF,
                                               const u16* __restrict__ out2,
                                               const float* __restrict__ invd,
                                               const float* __restrict__ bias,
                                               void* __restrict__ outp, int Mn) {
    int cnt = min(*gcnt, POOLCAP);
    int wid = blockIdx.x * 4 + (threadIdx.x >> 6);
    int lane = threadIdx.x & 63;
    int nw = gridDim.x * 4;
    for (int i = wid; i < cnt; i += nw) {
        int node = (int)pool[i].x;
        float id = invd[node];
        if (MODE == 0) {
            int sub = lane >> 4, l16 = lane & 15;
            const u16* tb = out2 + 128 + 8 * l16;
            float2 a[4];
#pragma unroll
            for (int q = 0; q < 4; q++) a[q] = make_float2(0.f, 0.f);
#pragma unroll
            for (int k = 0; k < 8; k++) {
                int s = colsF[node * 32 + sub + 4 * k] & IDXMASK;
                acc_u4p(a, *(const uint4*)(tb + (size_t)s * 256));
            }
            for (int j = 0; j < cnt; j++) {
                uint2 pe = pool[j];
                if ((int)pe.x == node && sub == (j & 3))
                    acc_u4p(a, *(const uint4*)(tb + (size_t)pe.y * 256));
            }
            float af[8] = {a[0].x, a[0].y, a[1].x, a[1].y, a[2].x, a[2].y, a[3].x, a[3].y};
#pragma unroll
            for (int j = 0; j < 8; j++) {
                af[j] += __shfl_xor(af[j], 16); af[j] += __shfl_xor(af[j], 32);
            }
            if (sub == 0) {
                uint4 sv = *(const uint4*)(out2 + (size_t)node * 256 + 8 * l16);
                float4 b0 = *(const float4*)(bias + 8 * l16);
                float4 b1 = *(const float4*)(bias + 8 * l16 + 4);
                float o0 = bf2f(sv.x & 0xffffu) + af[0] * id + b0.x;
                float o1 = bf2f(sv.x >> 16)     + af[1] * id + b0.y;
                float o2 = bf2f(sv.y & 0xffffu) + af[2] * id + b0.z;
                float o3 = bf2f(sv.y >> 16)     + af[3] * id + b0.w;
                float o4 = bf2f(sv.z & 0xffffu) + af[4] * id + b1.x;
                float o5 = bf2f(sv.z >> 16)     + af[5] * id + b1.y;
                float o6 = bf2f(sv.w & 0xffffu) + af[6] * id + b1.z;
                float o7 = bf2f(sv.w >> 16)     + af[7] * id + b1.w;
                o0 = fmaxf(o0, 0.f); o1 = fmaxf(o1, 0.f); o2 = fmaxf(o2, 0.f); o3 = fmaxf(o3, 0.f);
                o4 = fmaxf(o4, 0.f); o5 = fmaxf(o5, 0.f); o6 = fmaxf(o6, 0.f); o7 = fmaxf(o7, 0.f);
                uint4 w;
                w.x = (u32)f2bf(o0) | ((u32)f2bf(o1) << 16);
                w.y = (u32)f2bf(o2) | ((u32)f2bf(o3) << 16);
                w.z = (u32)f2bf(o4) | ((u32)f2bf(o5) << 16);
                w.w = (u32)f2bf(o6) | ((u32)f2bf(o7) << 16);
                *(uint4*)((u16*)outp + (size_t)node * 128 + 8 * l16) = w;
            }
        } else {
            int e8 = lane >> 3, l8 = lane & 7;
            const u16* tb = out2 + 64 + 8 * l8;
            float2 a[4];
#pragma unroll
            for (int q = 0; q < 4; q++) a[q] = make_float2(0.f, 0.f);
#pragma unroll
            for (int k = 0; k < 4; k++) {
                int s = colsF[node * 32 + e8 + 8 * k] & IDXMASK;
                acc_u4p(a, *(const uint4*)(tb + (size_t)s * 128));
            }
            for (int j = 0; j < cnt; j++) {
                uint2 pe = pool[j];
                if ((int)pe.x == node && e8 == (j & 7))
                    acc_u4p(a, *(const uint4*)(tb + (size_t)pe.y * 128));
            }
            float af[8] = {a[0].x, a[0].y, a[1].x, a[1].y, a[2].x, a[2].y, a[3].x, a[3].y};
#pragma unroll
            for (int j = 0; j < 8; j++) {
                af[j] += __shfl_xor(af[j], 8); af[j] += __shfl_xor(af[j], 16); af[j] += __shfl_xor(af[j], 32);
            }
            if (e8 == 0) {
                uint4 sv = *(const uint4*)(out2 + (size_t)node * 128 + 8 * l8);
                u32 sw[4] = {sv.x, sv.y, sv.z, sv.w};
                float* orow = (float*)outp + (size_t)node * 47;
#pragma unroll
                for (int j = 0; j < 8; j++) {
                    int c = 8 * l8 + j;
                    if (c < 47) {
                        float s = bf2f((j & 1) ? (sw[j >> 1] >> 16) : (sw[j >> 1] & 0xffffu));
                        orow[c] = s + af[j] * id + bias[c];
                    }
                }
            }
        }
    }
}

// ---------------- launch ----------------

extern "C" void kernel_launch(void* const* d_in, const int* in_sizes, int n_in,
                              void* d_out, int out_size, void* d_ws, size_t ws_size,
                              hipStream_t stream) {
    const float* x   = (const float*)d_in[0];
    const int*   src = (const int*)d_in[1];
    const int*   dst = (const int*)d_in[2];
    const float* ws0 = (const float*)d_in[3];
    const float* wn0 = (const float*)d_in[4];
    const float* b0  = (const float*)d_in[5];
    const float* ws1 = (const float*)d_in[6];
    const float* wn1 = (const float*)d_in[7];
    const float* b1  = (const float*)d_in[8];
    const float* ws2 = (const float*)d_in[9];
    const float* wn2 = (const float*)d_in[10];
    const float* b2  = (const float*)d_in[11];

    const int Nn = in_sizes[0] / 128;   // 100000
    const int E  = in_sizes[1];         // 1600000
    const int nBuckets = (Nn + 511) / 512;
    const int NnPad = nBuckets * 512;

    char* p = (char*)d_ws;
    auto alloc = [&](size_t bytes) -> void* {
        void* r = (void*)p;
        p += (bytes + 255) & ~(size_t)255;
        return r;
    };
    u16*   bufA   = (u16*)alloc((size_t)Nn * 128 * 2);            // h1 / h2
    u16*   out2   = (u16*)alloc(((size_t)Nn * 256 + 256) * 2);    // [s|t] per layer + zero pad row; pairs overlay
    u16*   wt0    = (u16*)alloc(256 * 128 * 2);
    u16*   wt1    = (u16*)alloc(256 * 128 * 2);
    u16*   wt2    = (u16*)alloc(128 * 128 * 2);
    float* invd   = (float*)alloc((size_t)Nn * 4);
    int*   colsF  = (int*)alloc((size_t)NnPad * 32 * 4);          // fixed-stride edge table (deg<<17|src)
    uint2* pool   = (uint2*)alloc((size_t)POOLCAP * 8);           // deg>32 overflow
    int*   gcnt   = (int*)alloc(256);
    int*   bcnt   = (int*)alloc(256 * 4);
    int*   boff   = (int*)alloc(257 * 4);
    int*   cursor = (int*)alloc(256 * 4);
    uint2* pairs  = (uint2*)out2;                                 // overlay: out2 unused until gemm layer 0

    hipMemsetAsync(bcnt, 0, 256 * 4, stream);
    hipMemsetAsync(gcnt, 0, 4, stream);
    // zero pad row for the 256-col layout (row Nn, byte offset Nn*512; beyond pairs overlay)
    hipMemsetAsync(out2 + (size_t)Nn * 256, 0, 512, stream);

    prep_w_all<<<320, 256, 0, stream>>>(ws0, wn0, wt0, ws1, wn1, wt1, ws2, wn2, wt2);

    hist256<<<512, 256, 0, stream>>>(dst, bcnt, E);
    scan256<<<1, 256, 0, stream>>>(bcnt, boff, cursor);

    bucket_scatter<<<(E + TILE - 1) / TILE, 512, 0, stream>>>(src, dst, cursor, pairs, E);
    build_csr3<<<nBuckets, 512, 0, stream>>>(pairs, boff, invd, colsF, pool, gcnt, Nn);

    dim3 ggrid((Nn + 63) / 64, 2);
    dim3 ggrid1((Nn + 63) / 64, 1);
    const int aggGrid = (Nn + 3) / 4;                    // 4 waves x 1 node
    // layer 0
    gemm_bf16<256, true><<<ggrid, 256, 0, stream>>>(x, wt0, out2, Nn);
    agg128f_k<true><<<aggGrid, 256, 0, stream>>>(out2, colsF, invd, b0, bufA, Nn);
    oflow_k<0><<<8, 256, 0, stream>>>(pool, gcnt, colsF, out2, invd, b0, bufA, Nn);
    // layer 1
    gemm_bf16<256, false><<<ggrid, 256, 0, stream>>>(bufA, wt1, out2, Nn);
    agg128f_k<true><<<aggGrid, 256, 0, stream>>>(out2, colsF, invd, b1, bufA, Nn);
    oflow_k<0><<<8, 256, 0, stream>>>(pool, gcnt, colsF, out2, invd, b1, bufA, Nn);
    // layer 2
    gemm_bf16<128, false><<<ggrid1, 256, 0, stream>>>(bufA, wt2, out2, Nn);
    // zero pad row for the 128-col layout (after gemm<128>, before its consumers)
    hipMemsetAsync(out2 + (size_t)Nn * 128, 0, 256, stream);
    agg_out8f_k<<<aggGrid, 256, 0, stream>>>(out2, colsF, invd, b2, (float*)d_out, Nn);
    oflow_k<1><<<8, 256, 0, stream>>>(pool, gcnt, colsF, out2, invd, b2, d_out, Nn);
}

// Round 7
// 388.820 us; speedup vs baseline: 1.0625x; 1.0625x over previous
//
#include <hip/hip_runtime.h>

typedef unsigned int u32;
typedef unsigned short u16;
typedef __attribute__((ext_vector_type(8))) short short8;   // 8 x bf16 (guide-verified frag type)
typedef __attribute__((ext_vector_type(4))) float f32x4;

#define POOLCAP 65536
#define IDXMASK 0x1ffff   // src index lives in bits 0..16; deg in bits 17..31

__device__ __forceinline__ u16 f2bf(float f) {
    u32 u = __float_as_uint(f);
    u32 r = (u + 0x7fffu + ((u >> 16) & 1u)) >> 16;   // RNE
    return (u16)r;
}
__device__ __forceinline__ float bf2f(u32 lo16) { return __uint_as_float(lo16 << 16); }

// packed accumulate: a[i] += {lo(w), hi(w)}
__device__ __forceinline__ void acc_u4p(float2* a, uint4 v) {
    u32 w[4] = {v.x, v.y, v.z, v.w};
#pragma unroll
    for (int i = 0; i < 4; i++) {
        a[i].x += __uint_as_float(w[i] << 16);
        a[i].y += __uint_as_float(w[i] & 0xffff0000u);
    }
}

// ---------------- prep + hist (fused: blocks [0,320) prep weights, [320,832) histogram) ----------------

__global__ __launch_bounds__(256) void prep_hist(const float* __restrict__ ws0, const float* __restrict__ wn0, u16* __restrict__ wt0,
                                                 const float* __restrict__ ws1, const float* __restrict__ wn1, u16* __restrict__ wt1,
                                                 const float* __restrict__ ws2, const float* __restrict__ wn2, u16* __restrict__ wt2,
                                                 const int* __restrict__ dst, int* __restrict__ bcnt, int E) {
    __shared__ int bins[256];
    int bid = blockIdx.x;
    if (bid < 320) {
        const float *ws, *wn;
        u16* wt;
        int dout, HW, local;
        if (bid < 128)      { ws = ws0; wn = wn0; wt = wt0; dout = 128; HW = 128; local = bid; }
        else if (bid < 256) { ws = ws1; wn = wn1; wt = wt1; dout = 128; HW = 128; local = bid - 128; }
        else                { ws = ws2; wn = wn2; wt = wt2; dout = 47;  HW = 64;  local = bid - 256; }
        int idx = local * 256 + threadIdx.x;   // idx = n*128 + k
        int n = idx >> 7, k = idx & 127;
        float v = 0.f;
        if (n < HW) { if (n < dout) v = ws[k * dout + n]; }
        else { int nn = n - HW; if (nn < dout) v = wn[k * dout + nn]; }
        wt[idx] = f2bf(v);
        return;
    }
    // histogram of dst >> 9 into 256 bucket counters (LDS-privatized)
    bins[threadIdx.x] = 0;
    __syncthreads();
    int hb = bid - 320;                        // 512 hist blocks
    int gid = hb * 256 + threadIdx.x;
    int stride = 512 * 256;
    const int4* d4 = (const int4*)dst;
    int n4 = E >> 2;
    for (int k = gid; k < n4; k += stride) {
        int4 v = d4[k];
        atomicAdd(&bins[v.x >> 9], 1);
        atomicAdd(&bins[v.y >> 9], 1);
        atomicAdd(&bins[v.z >> 9], 1);
        atomicAdd(&bins[v.w >> 9], 1);
    }
    for (int k = (n4 << 2) + gid; k < E; k += stride)
        atomicAdd(&bins[dst[k] >> 9], 1);
    __syncthreads();
    int b = bins[threadIdx.x];
    if (b) atomicAdd(&bcnt[threadIdx.x], b);
}

__global__ __launch_bounds__(256) void scan256(const int* __restrict__ bcnt,
                                               int* __restrict__ boff,
                                               int* __restrict__ cursor) {
    __shared__ int sm[256];
    int t = threadIdx.x;
    int v = bcnt[t];
    sm[t] = v;
    __syncthreads();
    for (int off = 1; off < 256; off <<= 1) {
        int u = (t >= off) ? sm[t - off] : 0;
        __syncthreads();
        sm[t] += u;
        __syncthreads();
    }
    int excl = sm[t] - v;
    boff[t] = excl;
    cursor[t] = excl;
    if (t == 255) boff[256] = sm[255];   // == E
}

// multisplit pass 1: tile -> LDS bucket-compaction -> contiguous bucket segments
#define TILE 4096
__global__ __launch_bounds__(512) void bucket_scatter(const int* __restrict__ src,
                                                      const int* __restrict__ dst,
                                                      int* __restrict__ cursor,
                                                      uint2* __restrict__ pairs, int E) {
    __shared__ uint2 sp[TILE];                         // 32 KB
    __shared__ int s_cnt[256], s_off[256], s_gpos[256], s_cnt2[256];
    const int tid = threadIdx.x;
    const int base = blockIdx.x * TILE;
    const int tn = min(TILE, E - base);
    if (tid < 256) { s_cnt[tid] = 0; s_cnt2[tid] = 0; }
    __syncthreads();
    int d[8], s[8];
#pragma unroll
    for (int j = 0; j < 8; j++) {
        int k = tid + j * 512;
        if (k < tn) {
            d[j] = dst[base + k];
            s[j] = src[base + k];
            atomicAdd(&s_cnt[d[j] >> 9], 1);
        } else d[j] = -1;
    }
    __syncthreads();
    if (tid < 256) s_off[tid] = s_cnt[tid];
    __syncthreads();
    for (int off = 1; off < 256; off <<= 1) {
        int v = 0;
        if (tid < 256 && tid >= off) v = s_off[tid - off];
        __syncthreads();
        if (tid < 256) s_off[tid] += v;
        __syncthreads();
    }
    if (tid < 256 && s_cnt[tid] > 0) s_gpos[tid] = atomicAdd(&cursor[tid], s_cnt[tid]);
    __syncthreads();
#pragma unroll
    for (int j = 0; j < 8; j++) {
        if (d[j] >= 0) {
            int b = d[j] >> 9;
            int p = atomicAdd(&s_cnt2[b], 1);
            sp[s_off[b] - s_cnt[b] + p] = make_uint2((u32)d[j], (u32)s[j]);
        }
    }
    __syncthreads();
    for (int k = tid; k < tn; k += 512) {
        uint2 pr = sp[k];
        int b = (int)(pr.x >> 9);
        pairs[s_gpos[b] + (k - (s_off[b] - s_cnt[b]))] = pr;
    }
}

// multisplit pass 2: FIXED-STRIDE placement, SINGLE pass over pairs.
//   colsF[node*32 + p] = (deg<<17) | src  (sentinel src = Nn -> zero row, synthesized
//   during writeback -- no pre-fill, no stash). Edges past 32 -> overflow pool
//   (handled inside the agg kernels; no separate oflow launch). invd computed here.
__global__ __launch_bounds__(512) void build_csr3(const uint2* __restrict__ pairs,
                                                  const int* __restrict__ boff,
                                                  float* __restrict__ invd,
                                                  int* __restrict__ colsF,
                                                  uint2* __restrict__ pool,
                                                  int* __restrict__ gcnt,
                                                  int Nn) {
    __shared__ int s_fix[512 * 32];                    // 64 KB fixed table
    __shared__ int s_cnt[512];
    const int tid = threadIdx.x;
    const int d0 = blockIdx.x * 512;
    const int nd = min(512, Nn - d0);
    const int base = boff[blockIdx.x];
    const int n = boff[blockIdx.x + 1] - base;
    s_cnt[tid] = 0;
    __syncthreads();
    for (int k = tid; k < n; k += 512) {               // single read of pairs, direct place
        uint2 pr = pairs[base + k];
        int dl = (int)pr.x - d0;
        int p = atomicAdd(&s_cnt[dl], 1);
        if (p < 32) s_fix[dl * 32 + p] = (int)pr.y;
        else {
            int q = atomicAdd(gcnt, 1);
            if (q < POOLCAP) pool[q] = make_uint2(pr.x, pr.y);
        }
    }
    __syncthreads();
    if (tid < nd) invd[d0 + tid] = 1.0f / (float)max(s_cnt[tid], 1);
    // coalesced writeback; sentinels + deg tag synthesized on the fly
    int4* dst4 = (int4*)(colsF + (size_t)d0 * 32);
    for (int k = tid; k < 512 * 32 / 4; k += 512) {
        int node = k >> 3;                             // 8 int4 per node
        int cnt = s_cnt[node];
        int dg = min(cnt, 0x7fff) << 17;
        int sb = (k & 7) * 4;
        int4 v;
        v.x = ((sb + 0 < cnt) ? s_fix[k * 4 + 0] : Nn) | dg;
        v.y = ((sb + 1 < cnt) ? s_fix[k * 4 + 1] : Nn) | dg;
        v.z = ((sb + 2 < cnt) ? s_fix[k * 4 + 2] : Nn) | dg;
        v.w = ((sb + 3 < cnt) ? s_fix[k * 4 + 3] : Nn) | dg;
        dst4[k] = v;
    }
}

// ---------------- fused GEMM: C[M][NCOLS] = A[M][128] @ Bt^T  (fp32 acc) ----------------
#define KDIM 128
#define KP 136

template <int NCOLS, bool AF32>
__global__ __launch_bounds__(256) void gemm_bf16(const void* __restrict__ Ap,
                                                 const u16* __restrict__ Bt,
                                                 u16* __restrict__ C, int M) {
    __shared__ u16 As[64 * KP];
    __shared__ u16 Bs[128 * KP];
    const int row0 = blockIdx.x * 64;
    const int col0 = blockIdx.y * 128;
    const int tid = threadIdx.x;

#pragma unroll
    for (int i = 0; i < 4; i++) {
        int idx = tid + i * 256;
        int r = idx >> 4, c = idx & 15;
        uint4 v = make_uint4(0, 0, 0, 0);
        if (row0 + r < M) {
            if (AF32) {
                const float* Af = (const float*)Ap;
                const float4* rowp = (const float4*)(Af + (size_t)(row0 + r) * KDIM);
                float4 f0 = rowp[2 * c];
                float4 f1 = rowp[2 * c + 1];
                v.x = (u32)f2bf(f0.x) | ((u32)f2bf(f0.y) << 16);
                v.y = (u32)f2bf(f0.z) | ((u32)f2bf(f0.w) << 16);
                v.z = (u32)f2bf(f1.x) | ((u32)f2bf(f1.y) << 16);
                v.w = (u32)f2bf(f1.z) | ((u32)f2bf(f1.w) << 16);
            } else {
                const u16* Ab = (const u16*)Ap;
                v = ((const uint4*)(Ab + (size_t)(row0 + r) * KDIM))[c];
            }
        }
        ((uint4*)(As + r * KP))[c] = v;
    }
#pragma unroll
    for (int i = 0; i < 8; i++) {
        int idx = tid + i * 256;
        int r = idx >> 4, c = idx & 15;
        uint4 v = ((const uint4*)(Bt + (size_t)(col0 + r) * KDIM))[c];
        ((uint4*)(Bs + r * KP))[c] = v;
    }
    __syncthreads();

    const int lane = tid & 63, wave = tid >> 6;
    const int quad = lane >> 4, l16 = lane & 15;
    const int wcol = wave * 32;

    f32x4 acc[4][2];
#pragma unroll
    for (int mt = 0; mt < 4; mt++)
#pragma unroll
        for (int nt = 0; nt < 2; nt++) acc[mt][nt] = (f32x4){0.f, 0.f, 0.f, 0.f};

#pragma unroll
    for (int kc = 0; kc < 4; kc++) {
        short8 a[4], b[2];
#pragma unroll
        for (int mt = 0; mt < 4; mt++)
            a[mt] = *(const short8*)(As + (size_t)(mt * 16 + l16) * KP + kc * 32 + quad * 8);
#pragma unroll
        for (int nt = 0; nt < 2; nt++)
            b[nt] = *(const short8*)(Bs + (size_t)(wcol + nt * 16 + l16) * KP + kc * 32 + quad * 8);
#pragma unroll
        for (int mt = 0; mt < 4; mt++)
#pragma unroll
            for (int nt = 0; nt < 2; nt++)
                acc[mt][nt] = __builtin_amdgcn_mfma_f32_16x16x32_bf16(a[mt], b[nt], acc[mt][nt], 0, 0, 0);
    }

    __syncthreads();
#pragma unroll
    for (int mt = 0; mt < 4; mt++)
#pragma unroll
        for (int i = 0; i < 4; i++) {
            int rl = mt * 16 + quad * 4 + i;
#pragma unroll
            for (int nt = 0; nt < 2; nt++)
                As[rl * KP + wcol + nt * 16 + l16] = f2bf(acc[mt][nt][i]);
        }
    __syncthreads();
#pragma unroll
    for (int it = 0; it < 4; it++) {
        int idx = tid + it * 256;
        int r = idx >> 4, c8 = idx & 15;
        if (row0 + r < M)
            *(uint4*)(C + (size_t)(row0 + r) * NCOLS + col0 + c8 * 8) =
                *(const uint4*)(As + r * KP + c8 * 8);
    }
}

// ---------------- 128-col aggregation, fixed-stride + scalar deg-gating + in-kernel overflow ----------------
// colsF[node*32+p] = (deg<<17)|src. All 8 gathers issue unconditionally (sentinel = hot
// zero-row line); accumulate rounds gated by SCALAR deg (wave-uniform, s_cbranch).
// deg>32 waves (Poisson(16): ~tens chip-wide) scan the pool themselves -- no oflow kernel.
template <bool RELU>
__global__ __launch_bounds__(256) void agg128f_k(const u16* __restrict__ out2,
                                                 const int* __restrict__ colsF,
                                                 const float* __restrict__ invd,
                                                 const float* __restrict__ bias,
                                                 const uint2* __restrict__ pool,
                                                 const int* __restrict__ gcnt,
                                                 u16* __restrict__ outp, int Mn) {
    int wave = threadIdx.x >> 6, lane = threadIdx.x & 63;
    int node = blockIdx.x * 4 + wave;
    if (node >= Mn) return;
    int sub = lane >> 4, l16 = lane & 15;
    const u16* tb = out2 + 128 + 8 * l16;
    const int* cp = colsF + node * 32 + sub;
    int s0 = cp[0],  s1 = cp[4],  s2 = cp[8],  s3 = cp[12];
    int s4 = cp[16], s5 = cp[20], s6 = cp[24], s7 = cp[28];
    const int deg = __builtin_amdgcn_readfirstlane(s0 >> 17);   // wave-uniform degree -> SGPR
    s0 &= IDXMASK; s1 &= IDXMASK; s2 &= IDXMASK; s3 &= IDXMASK;
    s4 &= IDXMASK; s5 &= IDXMASK; s6 &= IDXMASK; s7 &= IDXMASK;
    float id = invd[node];
    uint4 sv = *(const uint4*)(out2 + (size_t)node * 256 + 8 * l16);
    float4 b0 = *(const float4*)(bias + 8 * l16);
    float4 b1 = *(const float4*)(bias + 8 * l16 + 4);
    uint4 v0 = *(const uint4*)(tb + (size_t)s0 * 256);
    uint4 v1 = *(const uint4*)(tb + (size_t)s1 * 256);
    uint4 v2 = *(const uint4*)(tb + (size_t)s2 * 256);
    uint4 v3 = *(const uint4*)(tb + (size_t)s3 * 256);
    uint4 v4 = *(const uint4*)(tb + (size_t)s4 * 256);
    uint4 v5 = *(const uint4*)(tb + (size_t)s5 * 256);
    uint4 v6 = *(const uint4*)(tb + (size_t)s6 * 256);
    uint4 v7 = *(const uint4*)(tb + (size_t)s7 * 256);
    float2 a[4];
#pragma unroll
    for (int i = 0; i < 4; i++) a[i] = make_float2(0.f, 0.f);
    acc_u4p(a, v0);
    if (deg > 4)  acc_u4p(a, v1);
    if (deg > 8)  acc_u4p(a, v2);
    if (deg > 12) acc_u4p(a, v3);
    if (deg > 16) {
        acc_u4p(a, v4);
        if (deg > 20) acc_u4p(a, v5);
        if (deg > 24) acc_u4p(a, v6);
        if (deg > 28) acc_u4p(a, v7);
    }
    if (deg > 32) {                                    // in-kernel overflow (rare, scalar branch)
        int cnt = min(*gcnt, POOLCAP);
        for (int j = 0; j < cnt; j++) {
            uint2 pe = pool[j];
            if ((int)pe.x == node && sub == (j & 3))
                acc_u4p(a, *(const uint4*)(tb + (size_t)pe.y * 256));
        }
    }
    float af[8] = {a[0].x, a[0].y, a[1].x, a[1].y, a[2].x, a[2].y, a[3].x, a[3].y};
#pragma unroll
    for (int j = 0; j < 8; j++) {
        af[j] += __shfl_xor(af[j], 16); af[j] += __shfl_xor(af[j], 32);
    }
    if (sub == 0) {
        float o0 = bf2f(sv.x & 0xffffu) + af[0] * id + b0.x;
        float o1 = bf2f(sv.x >> 16)     + af[1] * id + b0.y;
        float o2 = bf2f(sv.y & 0xffffu) + af[2] * id + b0.z;
        float o3 = bf2f(sv.y >> 16)     + af[3] * id + b0.w;
        float o4 = bf2f(sv.z & 0xffffu) + af[4] * id + b1.x;
        float o5 = bf2f(sv.z >> 16)     + af[5] * id + b1.y;
        float o6 = bf2f(sv.w & 0xffffu) + af[6] * id + b1.z;
        float o7 = bf2f(sv.w >> 16)     + af[7] * id + b1.w;
        if (RELU) {
            o0 = fmaxf(o0, 0.f); o1 = fmaxf(o1, 0.f); o2 = fmaxf(o2, 0.f); o3 = fmaxf(o3, 0.f);
            o4 = fmaxf(o4, 0.f); o5 = fmaxf(o5, 0.f); o6 = fmaxf(o6, 0.f); o7 = fmaxf(o7, 0.f);
        }
        uint4 w;
        w.x = (u32)f2bf(o0) | ((u32)f2bf(o1) << 16);
        w.y = (u32)f2bf(o2) | ((u32)f2bf(o3) << 16);
        w.z = (u32)f2bf(o4) | ((u32)f2bf(o5) << 16);
        w.w = (u32)f2bf(o6) | ((u32)f2bf(o7) << 16);
        *(uint4*)(outp + (size_t)node * 128 + 8 * l16) = w;
    }
}

// ---------------- layer-2 aggregation, fixed-stride + scalar deg-gating + in-kernel overflow ----------------
__global__ __launch_bounds__(256) void agg_out8f_k(const u16* __restrict__ out2,
                                                   const int* __restrict__ colsF,
                                                   const float* __restrict__ invd,
                                                   const float* __restrict__ bias,
                                                   const uint2* __restrict__ pool,
                                                   const int* __restrict__ gcnt,
                                                   float* __restrict__ outp, int Mn) {
    int wave = threadIdx.x >> 6, lane = threadIdx.x & 63;
    int node = blockIdx.x * 4 + wave;
    if (node >= Mn) return;
    int e8 = lane >> 3, l8 = lane & 7;
    const u16* tb = out2 + 64 + 8 * l8;
    const int* cp = colsF + node * 32 + e8;
    int s0 = cp[0], s1 = cp[8], s2 = cp[16], s3 = cp[24];
    const int deg = __builtin_amdgcn_readfirstlane(s0 >> 17);
    s0 &= IDXMASK; s1 &= IDXMASK; s2 &= IDXMASK; s3 &= IDXMASK;
    float id = invd[node];
    uint4 sv = *(const uint4*)(out2 + (size_t)node * 128 + 8 * l8);
    uint4 v0 = *(const uint4*)(tb + (size_t)s0 * 128);
    uint4 v1 = *(const uint4*)(tb + (size_t)s1 * 128);
    uint4 v2 = *(const uint4*)(tb + (size_t)s2 * 128);
    uint4 v3 = *(const uint4*)(tb + (size_t)s3 * 128);
    float2 a[4];
#pragma unroll
    for (int i = 0; i < 4; i++) a[i] = make_float2(0.f, 0.f);
    acc_u4p(a, v0);
    if (deg > 8)  acc_u4p(a, v1);
    if (deg > 16) acc_u4p(a, v2);
    if (deg > 24) acc_u4p(a, v3);
    if (deg > 32) {                                    // in-kernel overflow (rare)
        int cnt = min(*gcnt, POOLCAP);
        for (int j = 0; j < cnt; j++) {
            uint2 pe = pool[j];
            if ((int)pe.x == node && e8 == (j & 7))
                acc_u4p(a, *(const uint4*)(tb + (size_t)pe.y * 128));
        }
    }
    float af[8] = {a[0].x, a[0].y, a[1].x, a[1].y, a[2].x, a[2].y, a[3].x, a[3].y};
#pragma unroll
    for (int j = 0; j < 8; j++) {
        af[j] += __shfl_xor(af[j], 8); af[j] += __shfl_xor(af[j], 16); af[j] += __shfl_xor(af[j], 32);
    }
    if (e8 == 0) {
        u32 sw[4] = {sv.x, sv.y, sv.z, sv.w};
        float* orow = outp + (size_t)node * 47;
#pragma unroll
        for (int j = 0; j < 8; j++) {
            int c = 8 * l8 + j;
            if (c < 47) {
                float s = bf2f((j & 1) ? (sw[j >> 1] >> 16) : (sw[j >> 1] & 0xffffu));
                orow[c] = s + af[j] * id + bias[c];
            }
        }
    }
}

// ---------------- launch ----------------

extern "C" void kernel_launch(void* const* d_in, const int* in_sizes, int n_in,
                              void* d_out, int out_size, void* d_ws, size_t ws_size,
                              hipStream_t stream) {
    const float* x   = (const float*)d_in[0];
    const int*   src = (const int*)d_in[1];
    const int*   dst = (const int*)d_in[2];
    const float* ws0 = (const float*)d_in[3];
    const float* wn0 = (const float*)d_in[4];
    const float* b0  = (const float*)d_in[5];
    const float* ws1 = (const float*)d_in[6];
    const float* wn1 = (const float*)d_in[7];
    const float* b1  = (const float*)d_in[8];
    const float* ws2 = (const float*)d_in[9];
    const float* wn2 = (const float*)d_in[10];
    const float* b2  = (const float*)d_in[11];

    const int Nn = in_sizes[0] / 128;   // 100000
    const int E  = in_sizes[1];         // 1600000
    const int nBuckets = (Nn + 511) / 512;
    const int NnPad = nBuckets * 512;

    char* p = (char*)d_ws;
    auto alloc = [&](size_t bytes) -> void* {
        void* r = (void*)p;
        p += (bytes + 255) & ~(size_t)255;
        return r;
    };
    u16*   bufA   = (u16*)alloc((size_t)Nn * 128 * 2);            // h1 / h2
    u16*   out2   = (u16*)alloc(((size_t)Nn * 256 + 256) * 2);    // [s|t] per layer + zero pad row; pairs overlay
    u16*   wt0    = (u16*)alloc(256 * 128 * 2);
    u16*   wt1    = (u16*)alloc(256 * 128 * 2);
    u16*   wt2    = (u16*)alloc(128 * 128 * 2);
    float* invd   = (float*)alloc((size_t)Nn * 4);
    int*   colsF  = (int*)alloc((size_t)NnPad * 32 * 4);          // fixed-stride edge table (deg<<17|src)
    uint2* pool   = (uint2*)alloc((size_t)POOLCAP * 8);           // deg>32 overflow
    int*   gcnt   = (int*)alloc(256);
    int*   bcnt   = (int*)alloc(256 * 4);
    int*   boff   = (int*)alloc(257 * 4);
    int*   cursor = (int*)alloc(256 * 4);
    uint2* pairs  = (uint2*)out2;                                 // overlay: out2 unused until gemm layer 0

    hipMemsetAsync(bcnt, 0, 256 * 4, stream);
    hipMemsetAsync(gcnt, 0, 4, stream);
    // zero pad row for the 256-col layout (row Nn, byte offset Nn*512; beyond pairs overlay)
    hipMemsetAsync(out2 + (size_t)Nn * 256, 0, 512, stream);

    // fused: weight transpose (320 blocks) + bucket histogram (512 blocks)
    prep_hist<<<832, 256, 0, stream>>>(ws0, wn0, wt0, ws1, wn1, wt1, ws2, wn2, wt2,
                                       dst, bcnt, E);
    scan256<<<1, 256, 0, stream>>>(bcnt, boff, cursor);

    bucket_scatter<<<(E + TILE - 1) / TILE, 512, 0, stream>>>(src, dst, cursor, pairs, E);
    build_csr3<<<nBuckets, 512, 0, stream>>>(pairs, boff, invd, colsF, pool, gcnt, Nn);

    dim3 ggrid((Nn + 63) / 64, 2);
    dim3 ggrid1((Nn + 63) / 64, 1);
    const int aggGrid = (Nn + 3) / 4;                    // 4 waves x 1 node
    // layer 0
    gemm_bf16<256, true><<<ggrid, 256, 0, stream>>>(x, wt0, out2, Nn);
    agg128f_k<true><<<aggGrid, 256, 0, stream>>>(out2, colsF, invd, b0, pool, gcnt, bufA, Nn);
    // layer 1
    gemm_bf16<256, false><<<ggrid, 256, 0, stream>>>(bufA, wt1, out2, Nn);
    agg128f_k<true><<<aggGrid, 256, 0, stream>>>(out2, colsF, invd, b1, pool, gcnt, bufA, Nn);
    // layer 2
    gemm_bf16<128, false><<<ggrid1, 256, 0, stream>>>(bufA, wt2, out2, Nn);
    // zero pad row for the 128-col layout (after gemm<128>, before its consumers)
    hipMemsetAsync(out2 + (size_t)Nn * 128, 0, 256, stream);
    agg_out8f_k<<<aggGrid, 256, 0, stream>>>(out2, colsF, invd, b2, pool, gcnt, (float*)d_out, Nn);
}

// Round 8
// 371.878 us; speedup vs baseline: 1.1109x; 1.0456x over previous
//
#include <hip/hip_runtime.h>

typedef unsigned int u32;
typedef unsigned short u16;
typedef __attribute__((ext_vector_type(8))) short short8;   // 8 x bf16 (guide-verified frag type)
typedef __attribute__((ext_vector_type(4))) float f32x4;

#define POOLCAP 65536
#define IDXMASK 0x1ffff   // src index lives in bits 0..16; deg in bits 17..31
#define BUCKCAP 12288     // fixed pairs segment per bucket (mean 8192, sigma~90 -> +45 sigma)

__device__ __forceinline__ u16 f2bf(float f) {
    u32 u = __float_as_uint(f);
    u32 r = (u + 0x7fffu + ((u >> 16) & 1u)) >> 16;   // RNE
    return (u16)r;
}
__device__ __forceinline__ float bf2f(u32 lo16) { return __uint_as_float(lo16 << 16); }

// packed accumulate: a[i] += {lo(w), hi(w)}
__device__ __forceinline__ void acc_u4p(float2* a, uint4 v) {
    u32 w[4] = {v.x, v.y, v.z, v.w};
#pragma unroll
    for (int i = 0; i < 4; i++) {
        a[i].x += __uint_as_float(w[i] << 16);
        a[i].y += __uint_as_float(w[i] & 0xffff0000u);
    }
}

// ---------------- scatter + weight-prep (fused; fixed-stride bucket segments, no histogram) ----------------
// blocks [0, NS): multisplit scatter into pairs[b*BUCKCAP + cursor[b]...]
// blocks [NS, NS+160): transposed-weight prep (64+64+32 blocks for wt0/wt1/wt2)
#define TILE 4096
__global__ __launch_bounds__(512) void scatter_prep(const int* __restrict__ src,
                                                    const int* __restrict__ dst,
                                                    int* __restrict__ cursor,
                                                    uint2* __restrict__ pairs, int E, int NS,
                                                    const float* __restrict__ ws0, const float* __restrict__ wn0, u16* __restrict__ wt0,
                                                    const float* __restrict__ ws1, const float* __restrict__ wn1, u16* __restrict__ wt1,
                                                    const float* __restrict__ ws2, const float* __restrict__ wn2, u16* __restrict__ wt2) {
    if (blockIdx.x >= NS) {                            // ---- weight prep ----
        int local = blockIdx.x - NS;
        const float *ws, *wn;
        u16* wt;
        int dout, HW;
        if (local < 64)       { ws = ws0; wn = wn0; wt = wt0; dout = 128; HW = 128; }
        else if (local < 128) { ws = ws1; wn = wn1; wt = wt1; dout = 128; HW = 128; local -= 64; }
        else                  { ws = ws2; wn = wn2; wt = wt2; dout = 47;  HW = 64;  local -= 128; }
        int idx = local * 512 + threadIdx.x;           // idx = n*128 + k
        int n = idx >> 7, k = idx & 127;
        float v = 0.f;
        if (n < HW) { if (n < dout) v = ws[k * dout + n]; }
        else { int nn = n - HW; if (nn < dout) v = wn[k * dout + nn]; }
        wt[idx] = f2bf(v);
        return;
    }
    // ---- bucket scatter ----
    __shared__ uint2 sp[TILE];                         // 32 KB
    __shared__ int s_cnt[256], s_off[256], s_gpos[256], s_cnt2[256];
    const int tid = threadIdx.x;
    const int base = blockIdx.x * TILE;
    const int tn = min(TILE, E - base);
    if (tid < 256) { s_cnt[tid] = 0; s_cnt2[tid] = 0; }
    __syncthreads();
    int d[8], s[8];
#pragma unroll
    for (int j = 0; j < 8; j++) {
        int k = tid + j * 512;
        if (k < tn) {
            d[j] = dst[base + k];
            s[j] = src[base + k];
            atomicAdd(&s_cnt[d[j] >> 9], 1);
        } else d[j] = -1;
    }
    __syncthreads();
    if (tid < 256) s_off[tid] = s_cnt[tid];
    __syncthreads();
    for (int off = 1; off < 256; off <<= 1) {
        int v = 0;
        if (tid < 256 && tid >= off) v = s_off[tid - off];
        __syncthreads();
        if (tid < 256) s_off[tid] += v;
        __syncthreads();
    }
    if (tid < 256 && s_cnt[tid] > 0) s_gpos[tid] = atomicAdd(&cursor[tid], s_cnt[tid]);
    __syncthreads();
#pragma unroll
    for (int j = 0; j < 8; j++) {
        if (d[j] >= 0) {
            int b = d[j] >> 9;
            int p = atomicAdd(&s_cnt2[b], 1);
            sp[s_off[b] - s_cnt[b] + p] = make_uint2((u32)d[j], (u32)s[j]);
        }
    }
    __syncthreads();
    for (int k = tid; k < tn; k += 512) {
        uint2 pr = sp[k];
        int b = (int)(pr.x >> 9);
        int pos = s_gpos[b] + (k - (s_off[b] - s_cnt[b]));
        if (pos < BUCKCAP)                             // overflow guard (~0 probability)
            pairs[(size_t)b * BUCKCAP + pos] = pr;
    }
}

// ---------------- build: FIXED-STRIDE placement, single pass over pairs ----------------
//   colsF[node*32 + p] = (deg<<17) | src  (sentinel src = Nn -> zero row, synthesized
//   during writeback). Edges past 32 -> overflow pool (handled inside agg kernels).
//   Bucket count read from cursor[b]. invd computed here.
__global__ __launch_bounds__(512) void build_csr3(const uint2* __restrict__ pairs,
                                                  const int* __restrict__ cursor,
                                                  float* __restrict__ invd,
                                                  int* __restrict__ colsF,
                                                  uint2* __restrict__ pool,
                                                  int* __restrict__ gcnt,
                                                  int Nn) {
    __shared__ int s_fix[512 * 32];                    // 64 KB fixed table
    __shared__ int s_cnt[512];
    const int tid = threadIdx.x;
    const int d0 = blockIdx.x * 512;
    const int nd = min(512, Nn - d0);
    const size_t base = (size_t)blockIdx.x * BUCKCAP;
    const int n = min(cursor[blockIdx.x], BUCKCAP);
    s_cnt[tid] = 0;
    __syncthreads();
    for (int k = tid; k < n; k += 512) {               // single read of pairs, direct place
        uint2 pr = pairs[base + k];
        int dl = (int)pr.x - d0;
        int p = atomicAdd(&s_cnt[dl], 1);
        if (p < 32) s_fix[dl * 32 + p] = (int)pr.y;
        else {
            int q = atomicAdd(gcnt, 1);
            if (q < POOLCAP) pool[q] = make_uint2(pr.x, pr.y);
        }
    }
    __syncthreads();
    if (tid < nd) invd[d0 + tid] = 1.0f / (float)max(s_cnt[tid], 1);
    // coalesced writeback; sentinels + deg tag synthesized on the fly
    int4* dst4 = (int4*)(colsF + (size_t)d0 * 32);
    for (int k = tid; k < 512 * 32 / 4; k += 512) {
        int node = k >> 3;                             // 8 int4 per node
        int cnt = s_cnt[node];
        int dg = min(cnt, 0x7fff) << 17;
        int sb = (k & 7) * 4;
        int4 v;
        v.x = ((sb + 0 < cnt) ? s_fix[k * 4 + 0] : Nn) | dg;
        v.y = ((sb + 1 < cnt) ? s_fix[k * 4 + 1] : Nn) | dg;
        v.z = ((sb + 2 < cnt) ? s_fix[k * 4 + 2] : Nn) | dg;
        v.w = ((sb + 3 < cnt) ? s_fix[k * 4 + 3] : Nn) | dg;
        dst4[k] = v;
    }
}

// ---------------- fused GEMM: C[M][NCOLS] = A[M][128] @ Bt^T  (fp32 acc) ----------------
// Store guard is row <= M: row M's accumulator is exactly zero (A rows >= M stage as
// zeros), so the GEMM writes the zero PAD ROW for the agg kernels for free (no memset).
#define KDIM 128
#define KP 136

template <int NCOLS, bool AF32>
__global__ __launch_bounds__(256) void gemm_bf16(const void* __restrict__ Ap,
                                                 const u16* __restrict__ Bt,
                                                 u16* __restrict__ C, int M) {
    __shared__ u16 As[64 * KP];
    __shared__ u16 Bs[128 * KP];
    const int row0 = blockIdx.x * 64;
    const int col0 = blockIdx.y * 128;
    const int tid = threadIdx.x;

#pragma unroll
    for (int i = 0; i < 4; i++) {
        int idx = tid + i * 256;
        int r = idx >> 4, c = idx & 15;
        uint4 v = make_uint4(0, 0, 0, 0);
        if (row0 + r < M) {
            if (AF32) {
                const float* Af = (const float*)Ap;
                const float4* rowp = (const float4*)(Af + (size_t)(row0 + r) * KDIM);
                float4 f0 = rowp[2 * c];
                float4 f1 = rowp[2 * c + 1];
                v.x = (u32)f2bf(f0.x) | ((u32)f2bf(f0.y) << 16);
                v.y = (u32)f2bf(f0.z) | ((u32)f2bf(f0.w) << 16);
                v.z = (u32)f2bf(f1.x) | ((u32)f2bf(f1.y) << 16);
                v.w = (u32)f2bf(f1.z) | ((u32)f2bf(f1.w) << 16);
            } else {
                const u16* Ab = (const u16*)Ap;
                v = ((const uint4*)(Ab + (size_t)(row0 + r) * KDIM))[c];
            }
        }
        ((uint4*)(As + r * KP))[c] = v;
    }
#pragma unroll
    for (int i = 0; i < 8; i++) {
        int idx = tid + i * 256;
        int r = idx >> 4, c = idx & 15;
        uint4 v = ((const uint4*)(Bt + (size_t)(col0 + r) * KDIM))[c];
        ((uint4*)(Bs + r * KP))[c] = v;
    }
    __syncthreads();

    const int lane = tid & 63, wave = tid >> 6;
    const int quad = lane >> 4, l16 = lane & 15;
    const int wcol = wave * 32;

    f32x4 acc[4][2];
#pragma unroll
    for (int mt = 0; mt < 4; mt++)
#pragma unroll
        for (int nt = 0; nt < 2; nt++) acc[mt][nt] = (f32x4){0.f, 0.f, 0.f, 0.f};

#pragma unroll
    for (int kc = 0; kc < 4; kc++) {
        short8 a[4], b[2];
#pragma unroll
        for (int mt = 0; mt < 4; mt++)
            a[mt] = *(const short8*)(As + (size_t)(mt * 16 + l16) * KP + kc * 32 + quad * 8);
#pragma unroll
        for (int nt = 0; nt < 2; nt++)
            b[nt] = *(const short8*)(Bs + (size_t)(wcol + nt * 16 + l16) * KP + kc * 32 + quad * 8);
#pragma unroll
        for (int mt = 0; mt < 4; mt++)
#pragma unroll
            for (int nt = 0; nt < 2; nt++)
                acc[mt][nt] = __builtin_amdgcn_mfma_f32_16x16x32_bf16(a[mt], b[nt], acc[mt][nt], 0, 0, 0);
    }

    __syncthreads();
#pragma unroll
    for (int mt = 0; mt < 4; mt++)
#pragma unroll
        for (int i = 0; i < 4; i++) {
            int rl = mt * 16 + quad * 4 + i;
#pragma unroll
            for (int nt = 0; nt < 2; nt++)
                As[rl * KP + wcol + nt * 16 + l16] = f2bf(acc[mt][nt][i]);
        }
    __syncthreads();
#pragma unroll
    for (int it = 0; it < 4; it++) {
        int idx = tid + it * 256;
        int r = idx >> 4, c8 = idx & 15;
        if (row0 + r <= M)                             // <= M: row M = zero pad row
            *(uint4*)(C + (size_t)(row0 + r) * NCOLS + col0 + c8 * 8) =
                *(const uint4*)(As + r * KP + c8 * 8);
    }
}

// ---------------- 128-col aggregation, fixed-stride + scalar deg-gating + in-kernel overflow ----------------
// colsF[node*32+p] = (deg<<17)|src. All 8 gathers issue unconditionally (sentinel = hot
// zero-row line); accumulate rounds gated by SCALAR deg (wave-uniform, s_cbranch).
// deg>32 waves (Poisson(16): ~tens chip-wide) scan the pool themselves.
template <bool RELU>
__global__ __launch_bounds__(256) void agg128f_k(const u16* __restrict__ out2,
                                                 const int* __restrict__ colsF,
                                                 const float* __restrict__ invd,
                                                 const float* __restrict__ bias,
                                                 const uint2* __restrict__ pool,
                                                 const int* __restrict__ gcnt,
                                                 u16* __restrict__ outp, int Mn) {
    int wave = threadIdx.x >> 6, lane = threadIdx.x & 63;
    int node = blockIdx.x * 4 + wave;
    if (node >= Mn) return;
    int sub = lane >> 4, l16 = lane & 15;
    const u16* tb = out2 + 128 + 8 * l16;
    const int* cp = colsF + node * 32 + sub;
    int s0 = cp[0],  s1 = cp[4],  s2 = cp[8],  s3 = cp[12];
    int s4 = cp[16], s5 = cp[20], s6 = cp[24], s7 = cp[28];
    const int deg = __builtin_amdgcn_readfirstlane(s0 >> 17);   // wave-uniform degree -> SGPR
    s0 &= IDXMASK; s1 &= IDXMASK; s2 &= IDXMASK; s3 &= IDXMASK;
    s4 &= IDXMASK; s5 &= IDXMASK; s6 &= IDXMASK; s7 &= IDXMASK;
    float id = invd[node];
    uint4 sv = *(const uint4*)(out2 + (size_t)node * 256 + 8 * l16);
    float4 b0 = *(const float4*)(bias + 8 * l16);
    float4 b1 = *(const float4*)(bias + 8 * l16 + 4);
    uint4 v0 = *(const uint4*)(tb + (size_t)s0 * 256);
    uint4 v1 = *(const uint4*)(tb + (size_t)s1 * 256);
    uint4 v2 = *(const uint4*)(tb + (size_t)s2 * 256);
    uint4 v3 = *(const uint4*)(tb + (size_t)s3 * 256);
    uint4 v4 = *(const uint4*)(tb + (size_t)s4 * 256);
    uint4 v5 = *(const uint4*)(tb + (size_t)s5 * 256);
    uint4 v6 = *(const uint4*)(tb + (size_t)s6 * 256);
    uint4 v7 = *(const uint4*)(tb + (size_t)s7 * 256);
    float2 a[4];
#pragma unroll
    for (int i = 0; i < 4; i++) a[i] = make_float2(0.f, 0.f);
    acc_u4p(a, v0);
    if (deg > 4)  acc_u4p(a, v1);
    if (deg > 8)  acc_u4p(a, v2);
    if (deg > 12) acc_u4p(a, v3);
    if (deg > 16) {
        acc_u4p(a, v4);
        if (deg > 20) acc_u4p(a, v5);
        if (deg > 24) acc_u4p(a, v6);
        if (deg > 28) acc_u4p(a, v7);
    }
    if (deg > 32) {                                    // in-kernel overflow (rare, scalar branch)
        int cnt = min(*gcnt, POOLCAP);
        for (int j = 0; j < cnt; j++) {
            uint2 pe = pool[j];
            if ((int)pe.x == node && sub == (j & 3))
                acc_u4p(a, *(const uint4*)(tb + (size_t)pe.y * 256));
        }
    }
    float af[8] = {a[0].x, a[0].y, a[1].x, a[1].y, a[2].x, a[2].y, a[3].x, a[3].y};
#pragma unroll
    for (int j = 0; j < 8; j++) {
        af[j] += __shfl_xor(af[j], 16); af[j] += __shfl_xor(af[j], 32);
    }
    if (sub == 0) {
        float o0 = bf2f(sv.x & 0xffffu) + af[0] * id + b0.x;
        float o1 = bf2f(sv.x >> 16)     + af[1] * id + b0.y;
        float o2 = bf2f(sv.y & 0xffffu) + af[2] * id + b0.z;
        float o3 = bf2f(sv.y >> 16)     + af[3] * id + b0.w;
        float o4 = bf2f(sv.z & 0xffffu) + af[4] * id + b1.x;
        float o5 = bf2f(sv.z >> 16)     + af[5] * id + b1.y;
        float o6 = bf2f(sv.w & 0xffffu) + af[6] * id + b1.z;
        float o7 = bf2f(sv.w >> 16)     + af[7] * id + b1.w;
        if (RELU) {
            o0 = fmaxf(o0, 0.f); o1 = fmaxf(o1, 0.f); o2 = fmaxf(o2, 0.f); o3 = fmaxf(o3, 0.f);
            o4 = fmaxf(o4, 0.f); o5 = fmaxf(o5, 0.f); o6 = fmaxf(o6, 0.f); o7 = fmaxf(o7, 0.f);
        }
        uint4 w;
        w.x = (u32)f2bf(o0) | ((u32)f2bf(o1) << 16);
        w.y = (u32)f2bf(o2) | ((u32)f2bf(o3) << 16);
        w.z = (u32)f2bf(o4) | ((u32)f2bf(o5) << 16);
        w.w = (u32)f2bf(o6) | ((u32)f2bf(o7) << 16);
        *(uint4*)(outp + (size_t)node * 128 + 8 * l16) = w;
    }
}

// ---------------- layer-2 aggregation, fixed-stride + scalar deg-gating + in-kernel overflow ----------------
__global__ __launch_bounds__(256) void agg_out8f_k(const u16* __restrict__ out2,
                                                   const int* __restrict__ colsF,
                                                   const float* __restrict__ invd,
                                                   const float* __restrict__ bias,
                                                   const uint2* __restrict__ pool,
                                                   const int* __restrict__ gcnt,
                                                   float* __restrict__ outp, int Mn) {
    int wave = threadIdx.x >> 6, lane = threadIdx.x & 63;
    int node = blockIdx.x * 4 + wave;
    if (node >= Mn) return;
    int e8 = lane >> 3, l8 = lane & 7;
    const u16* tb = out2 + 64 + 8 * l8;
    const int* cp = colsF + node * 32 + e8;
    int s0 = cp[0], s1 = cp[8], s2 = cp[16], s3 = cp[24];
    const int deg = __builtin_amdgcn_readfirstlane(s0 >> 17);
    s0 &= IDXMASK; s1 &= IDXMASK; s2 &= IDXMASK; s3 &= IDXMASK;
    float id = invd[node];
    uint4 sv = *(const uint4*)(out2 + (size_t)node * 128 + 8 * l8);
    uint4 v0 = *(const uint4*)(tb + (size_t)s0 * 128);
    uint4 v1 = *(const uint4*)(tb + (size_t)s1 * 128);
    uint4 v2 = *(const uint4*)(tb + (size_t)s2 * 128);
    uint4 v3 = *(const uint4*)(tb + (size_t)s3 * 128);
    float2 a[4];
#pragma unroll
    for (int i = 0; i < 4; i++) a[i] = make_float2(0.f, 0.f);
    acc_u4p(a, v0);
    if (deg > 8)  acc_u4p(a, v1);
    if (deg > 16) acc_u4p(a, v2);
    if (deg > 24) acc_u4p(a, v3);
    if (deg > 32) {                                    // in-kernel overflow (rare)
        int cnt = min(*gcnt, POOLCAP);
        for (int j = 0; j < cnt; j++) {
            uint2 pe = pool[j];
            if ((int)pe.x == node && e8 == (j & 7))
                acc_u4p(a, *(const uint4*)(tb + (size_t)pe.y * 128));
        }
    }
    float af[8] = {a[0].x, a[0].y, a[1].x, a[1].y, a[2].x, a[2].y, a[3].x, a[3].y};
#pragma unroll
    for (int j = 0; j < 8; j++) {
        af[j] += __shfl_xor(af[j], 8); af[j] += __shfl_xor(af[j], 16); af[j] += __shfl_xor(af[j], 32);
    }
    if (e8 == 0) {
        u32 sw[4] = {sv.x, sv.y, sv.z, sv.w};
        float* orow = outp + (size_t)node * 47;
#pragma unroll
        for (int j = 0; j < 8; j++) {
            int c = 8 * l8 + j;
            if (c < 47) {
                float s = bf2f((j & 1) ? (sw[j >> 1] >> 16) : (sw[j >> 1] & 0xffffu));
                orow[c] = s + af[j] * id + bias[c];
            }
        }
    }
}

// ---------------- launch ----------------

extern "C" void kernel_launch(void* const* d_in, const int* in_sizes, int n_in,
                              void* d_out, int out_size, void* d_ws, size_t ws_size,
                              hipStream_t stream) {
    const float* x   = (const float*)d_in[0];
    const int*   src = (const int*)d_in[1];
    const int*   dst = (const int*)d_in[2];
    const float* ws0 = (const float*)d_in[3];
    const float* wn0 = (const float*)d_in[4];
    const float* b0  = (const float*)d_in[5];
    const float* ws1 = (const float*)d_in[6];
    const float* wn1 = (const float*)d_in[7];
    const float* b1  = (const float*)d_in[8];
    const float* ws2 = (const float*)d_in[9];
    const float* wn2 = (const float*)d_in[10];
    const float* b2  = (const float*)d_in[11];

    const int Nn = in_sizes[0] / 128;   // 100000
    const int E  = in_sizes[1];         // 1600000
    const int nBuckets = (Nn + 511) / 512;
    const int NnPad = nBuckets * 512;
    const int NS = (E + TILE - 1) / TILE;              // scatter blocks

    char* p = (char*)d_ws;
    auto alloc = [&](size_t bytes) -> void* {
        void* r = (void*)p;
        p += (bytes + 255) & ~(size_t)255;
        return r;
    };
    u16*   bufA   = (u16*)alloc((size_t)Nn * 128 * 2);            // h1 / h2
    u16*   out2   = (u16*)alloc(((size_t)Nn * 256 + 256) * 2);    // [s|t] per layer + zero pad row; pairs overlay
    u16*   wt0    = (u16*)alloc(256 * 128 * 2);
    u16*   wt1    = (u16*)alloc(256 * 128 * 2);
    u16*   wt2    = (u16*)alloc(128 * 128 * 2);
    float* invd   = (float*)alloc((size_t)Nn * 4);
    int*   colsF  = (int*)alloc((size_t)NnPad * 32 * 4);          // fixed-stride edge table (deg<<17|src)
    uint2* pool   = (uint2*)alloc((size_t)POOLCAP * 8);           // deg>32 overflow
    int*   ctrl   = (int*)alloc(257 * 4);                         // cursor[256] + gcnt (one memset)
    int*   cursor = ctrl;
    int*   gcnt   = ctrl + 256;
    uint2* pairs  = (uint2*)out2;                                 // overlay (256*BUCKCAP*8 = 25.2 MB < 51.2 MB)

    hipMemsetAsync(ctrl, 0, 257 * 4, stream);

    // fused: bucket scatter (NS blocks) + weight prep (160 blocks)
    scatter_prep<<<NS + 160, 512, 0, stream>>>(src, dst, cursor, pairs, E, NS,
                                               ws0, wn0, wt0, ws1, wn1, wt1, ws2, wn2, wt2);
    build_csr3<<<nBuckets, 512, 0, stream>>>(pairs, cursor, invd, colsF, pool, gcnt, Nn);

    dim3 ggrid((Nn + 63) / 64, 2);
    dim3 ggrid1((Nn + 63) / 64, 1);
    const int aggGrid = (Nn + 3) / 4;                    // 4 waves x 1 node
    // layer 0 (gemm writes the zero pad row at node Nn itself)
    gemm_bf16<256, true><<<ggrid, 256, 0, stream>>>(x, wt0, out2, Nn);
    agg128f_k<true><<<aggGrid, 256, 0, stream>>>(out2, colsF, invd, b0, pool, gcnt, bufA, Nn);
    // layer 1
    gemm_bf16<256, false><<<ggrid, 256, 0, stream>>>(bufA, wt1, out2, Nn);
    agg128f_k<true><<<aggGrid, 256, 0, stream>>>(out2, colsF, invd, b1, pool, gcnt, bufA, Nn);
    // layer 2
    gemm_bf16<128, false><<<ggrid1, 256, 0, stream>>>(bufA, wt2, out2, Nn);
    agg_out8f_k<<<aggGrid, 256, 0, stream>>>(out2, colsF, invd, b2, pool, gcnt, (float*)d_out, Nn);
}